// Round 1
// baseline (1557.927 us; speedup 1.0000x reference)
//
#include <hip/hip_runtime.h>
#include <hip/hip_bf16.h>
#include <math.h>

#define N_NODES 100000
#define N_EDGES 3200000
#define N_GRAPHS 512
#define BN_EPS 1e-5f

// ---------------- CSR build ----------------

__global__ void k_count(const int* __restrict__ dst, int* __restrict__ cnt) {
    int e = blockIdx.x * blockDim.x + threadIdx.x;
    if (e < N_EDGES) atomicAdd(&cnt[dst[e]], 1);
}

__global__ void k_dis(const int* __restrict__ cnt, float* __restrict__ dis) {
    int n = blockIdx.x * blockDim.x + threadIdx.x;
    if (n < N_NODES) dis[n] = rsqrtf(1.0f + (float)cnt[n]);  // deg includes self-loop
}

// block-wise exclusive scan (1024/block)
__global__ void k_scan_block(const int* __restrict__ cnt, int* __restrict__ offs,
                             int* __restrict__ bsum) {
    __shared__ int sd[1024];
    int tid = threadIdx.x;
    int i = blockIdx.x * 1024 + tid;
    int v = (i < N_NODES) ? cnt[i] : 0;
    sd[tid] = v;
    __syncthreads();
    for (int off = 1; off < 1024; off <<= 1) {
        int t = (tid >= off) ? sd[tid - off] : 0;
        __syncthreads();
        sd[tid] += t;
        __syncthreads();
    }
    if (i < N_NODES) offs[i] = sd[tid] - v;  // exclusive
    if (tid == 1023) bsum[blockIdx.x] = sd[1023];
}

__global__ void k_scan_bsum(int* __restrict__ bsum, int nb, int* __restrict__ offs) {
    if (blockIdx.x == 0 && threadIdx.x == 0) {
        int run = 0;
        for (int b = 0; b < nb; ++b) { int t = bsum[b]; bsum[b] = run; run += t; }
        offs[N_NODES] = N_EDGES;
    }
}

__global__ void k_scan_add(int* __restrict__ offs, const int* __restrict__ bsum) {
    int i = blockIdx.x * blockDim.x + threadIdx.x;
    if (i < N_NODES) offs[i] += bsum[i >> 10];
}

__global__ void k_fill(const int* __restrict__ src, const int* __restrict__ dst,
                       const int* __restrict__ offs, int* __restrict__ cursor,
                       int* __restrict__ csr) {
    int e = blockIdx.x * blockDim.x + threadIdx.x;
    if (e < N_EDGES) {
        int d = dst[e];
        int pos = offs[d] + atomicAdd(&cursor[d], 1);
        csr[pos] = src[e];
    }
}

// ---------------- dense matmul h[N,FIN] @ W[FIN,FOUT] ----------------

template <int FIN, int FOUT>
__global__ void k_mm(const float* __restrict__ h, const float* __restrict__ W,
                     float* __restrict__ out) {
    __shared__ float sW[FIN * FOUT];
    for (int i = threadIdx.x; i < FIN * FOUT; i += blockDim.x) sW[i] = W[i];
    __syncthreads();
    int gid = blockIdx.x * blockDim.x + threadIdx.x;
    if (gid >= N_NODES * FOUT) return;
    int n = gid / FOUT, f = gid % FOUT;  // FOUT is power of 2 -> shifts
    float acc = 0.f;
#pragma unroll
    for (int i = 0; i < FIN; ++i) acc += h[n * FIN + i] * sW[i * FOUT + f];
    out[gid] = acc;
}

// ---------------- GCN aggregation: out[n] = dn*sum(dis[s]*hW[s]) + dn^2*hW[n] ----------------

template <int FOUT>
__global__ void k_agg(const float* __restrict__ hW, const int* __restrict__ offs,
                      const int* __restrict__ csr, const float* __restrict__ dis,
                      float* __restrict__ out) {
    int gid = blockIdx.x * blockDim.x + threadIdx.x;
    if (gid >= N_NODES * FOUT) return;
    int n = gid / FOUT, f = gid % FOUT;
    int e0 = offs[n], e1 = offs[n + 1];
    float acc = 0.f;
    for (int e = e0; e < e1; ++e) {
        int s = csr[e];
        acc += dis[s] * hW[s * FOUT + f];
    }
    float dn = dis[n];
    out[gid] = dn * acc + dn * dn * hW[n * FOUT + f];
}

// ---------------- BN stats over y = relu(conv + bias) ----------------

template <int FOUT>
__global__ void k_stats(const float* __restrict__ conv, const float* __restrict__ bias,
                        float* __restrict__ stats) {
    constexpr int GP = 256 / FOUT;
    int f = threadIdx.x % FOUT, g = threadIdx.x / FOUT;
    float bf = bias[f];
    float s = 0.f, s2 = 0.f;
    for (int n = blockIdx.x * GP + g; n < N_NODES; n += gridDim.x * GP) {
        float y = conv[n * FOUT + f] + bf;
        y = y > 0.f ? y : 0.f;
        s += y;
        s2 += y * y;
    }
    __shared__ float ls[256], ls2[256];
    ls[threadIdx.x] = s;
    ls2[threadIdx.x] = s2;
    __syncthreads();
    if (g == 0) {
        for (int gg = 1; gg < GP; ++gg) {
            s += ls[gg * FOUT + f];
            s2 += ls2[gg * FOUT + f];
        }
        atomicAdd(&stats[f], s);
        atomicAdd(&stats[FOUT + f], s2);
    }
}

template <int FOUT>
__global__ void k_bnprep(const float* __restrict__ stats, const float* __restrict__ gamma,
                         const float* __restrict__ beta, float* __restrict__ bnp) {
    int f = threadIdx.x;
    if (f >= FOUT) return;
    float inv_n = 1.0f / (float)N_NODES;
    float m = stats[f] * inv_n;
    float v = stats[FOUT + f] * inv_n - m * m;
    float a = gamma[f] * rsqrtf(v + BN_EPS);
    bnp[f] = a;
    bnp[FOUT + f] = beta[f] - m * a;
}

template <int FOUT>
__global__ void k_apply(float* __restrict__ hc, const float* __restrict__ bias,
                        const float* __restrict__ bnp) {
    int gid = blockIdx.x * blockDim.x + threadIdx.x;
    if (gid >= N_NODES * FOUT) return;
    int f = gid % FOUT;
    float y = hc[gid] + bias[f];
    y = y > 0.f ? y : 0.f;
    hc[gid] = bnp[f] * y + bnp[FOUT + f];
}

// ---------------- pooling (batch_index sorted) + head ----------------

__device__ __forceinline__ int lower_bound_dev(const int* __restrict__ a, int val) {
    int lo = 0, hi = N_NODES;
    while (lo < hi) {
        int mid = (lo + hi) >> 1;
        if (a[mid] < val) lo = mid + 1; else hi = mid;
    }
    return lo;
}

__global__ void k_pool(const float* __restrict__ h, const int* __restrict__ batch,
                       float* __restrict__ pooled) {
    int g = blockIdx.x;       // 0..511
    int f = threadIdx.x;      // 0..127
    int s = lower_bound_dev(batch, g);
    int e = lower_bound_dev(batch, g + 1);
    float m = -INFINITY;
    for (int n = s; n < e; ++n) m = fmaxf(m, h[n * 128 + f]);
    pooled[g * 128 + f] = m;
}

__global__ void k_head(const float* __restrict__ pooled, const float* __restrict__ Wl,
                       const float* __restrict__ bl, float* __restrict__ out) {
    int g = blockIdx.x * blockDim.x + threadIdx.x;
    if (g >= N_GRAPHS) return;
    float l0 = bl[0], l1 = bl[1], l2 = bl[2];
    for (int i = 0; i < 128; ++i) {
        float p = pooled[g * 128 + i];
        l0 += p * Wl[i * 3 + 0];
        l1 += p * Wl[i * 3 + 1];
        l2 += p * Wl[i * 3 + 2];
    }
    float mx = fmaxf(l0, fmaxf(l1, l2));
    float lse = mx + logf(expf(l0 - mx) + expf(l1 - mx) + expf(l2 - mx));
    out[g * 3 + 0] = l0 - lse;
    out[g * 3 + 1] = l1 - lse;
    out[g * 3 + 2] = l2 - lse;
}

// ---------------- launch ----------------

extern "C" void kernel_launch(void* const* d_in, const int* in_sizes, int n_in,
                              void* d_out, int out_size, void* d_ws, size_t ws_size,
                              hipStream_t stream) {
    const float* x   = (const float*)d_in[0];
    const int* ei    = (const int*)d_in[1];
    const int* src   = ei;
    const int* dst   = ei + N_EDGES;
    const int* batch = (const int*)d_in[2];
    const float *W1 = (const float*)d_in[3],  *b1 = (const float*)d_in[4];
    const float *g1 = (const float*)d_in[5],  *be1 = (const float*)d_in[6];
    const float *W2 = (const float*)d_in[7],  *b2 = (const float*)d_in[8];
    const float *g2 = (const float*)d_in[9],  *be2 = (const float*)d_in[10];
    const float *W3 = (const float*)d_in[11], *b3 = (const float*)d_in[12];
    const float *g3 = (const float*)d_in[13], *be3 = (const float*)d_in[14];
    const float *Wl = (const float*)d_in[15], *bl = (const float*)d_in[16];
    float* out = (float*)d_out;

    // workspace carve (4-byte elements)
    int* base = (int*)d_ws;
    size_t o = 0;
    int* cnt     = base + o; o += N_NODES;
    int* cursor  = base + o; o += N_NODES;
    float* stats = (float*)(base + o); o += 256;
    float* bnp   = (float*)(base + o); o += 256;
    int* offs    = base + o; o += N_NODES + 1;
    int* bsum    = base + o; o += 128;
    int* csr     = base + o; o += N_EDGES;
    float* dis   = (float*)(base + o); o += N_NODES;
    float* pooled= (float*)(base + o); o += (size_t)N_GRAPHS * 128;
    float* bufA  = (float*)(base + o); o += (size_t)N_NODES * 128;
    float* bufC  = (float*)(base + o); o += (size_t)N_NODES * 128;
    if (ws_size < o * 4) return;  // workspace too small -> fail loudly via wrong output

    const int TB = 256;
    const int gridE = (N_EDGES + TB - 1) / TB;
    const int gridN = (N_NODES + TB - 1) / TB;
    const int nb_scan = (N_NODES + 1023) / 1024;  // 98

    // zero cnt + cursor
    hipMemsetAsync(base, 0, (size_t)2 * N_NODES * 4, stream);

    // CSR + norm
    k_count<<<gridE, TB, 0, stream>>>(dst, cnt);
    k_dis<<<gridN, TB, 0, stream>>>(cnt, dis);
    k_scan_block<<<nb_scan, 1024, 0, stream>>>(cnt, offs, bsum);
    k_scan_bsum<<<1, 1, 0, stream>>>(bsum, nb_scan, offs);
    k_scan_add<<<gridN, TB, 0, stream>>>(offs, bsum);
    k_fill<<<gridE, TB, 0, stream>>>(src, dst, offs, cursor, csr);

    // ---- layer 1: 2 -> 8 ----
    {
        const int g8 = (N_NODES * 8 + TB - 1) / TB;
        k_mm<2, 8><<<g8, TB, 0, stream>>>(x, W1, bufA);
        k_agg<8><<<g8, TB, 0, stream>>>(bufA, offs, csr, dis, bufC);
        hipMemsetAsync(stats, 0, 1024, stream);
        k_stats<8><<<256, 256, 0, stream>>>(bufC, b1, stats);
        k_bnprep<8><<<1, 8, 0, stream>>>(stats, g1, be1, bnp);
        k_apply<8><<<g8, TB, 0, stream>>>(bufC, b1, bnp);
    }
    // ---- layer 2: 8 -> 32 ----
    {
        const int g32 = (N_NODES * 32 + TB - 1) / TB;
        k_mm<8, 32><<<g32, TB, 0, stream>>>(bufC, W2, bufA);
        k_agg<32><<<g32, TB, 0, stream>>>(bufA, offs, csr, dis, bufC);
        hipMemsetAsync(stats, 0, 1024, stream);
        k_stats<32><<<256, 256, 0, stream>>>(bufC, b2, stats);
        k_bnprep<32><<<1, 32, 0, stream>>>(stats, g2, be2, bnp);
        k_apply<32><<<g32, TB, 0, stream>>>(bufC, b2, bnp);
    }
    // ---- layer 3: 32 -> 128 ----
    {
        const int g128 = (N_NODES * 128 + TB - 1) / TB;
        k_mm<32, 128><<<g128, TB, 0, stream>>>(bufC, W3, bufA);
        k_agg<128><<<g128, TB, 0, stream>>>(bufA, offs, csr, dis, bufC);
        hipMemsetAsync(stats, 0, 1024, stream);
        k_stats<128><<<256, 256, 0, stream>>>(bufC, b3, stats);
        k_bnprep<128><<<1, 128, 0, stream>>>(stats, g3, be3, bnp);
        k_apply<128><<<g128, TB, 0, stream>>>(bufC, b3, bnp);
    }

    // pool + head
    k_pool<<<N_GRAPHS, 128, 0, stream>>>(bufC, batch, pooled);
    k_head<<<(N_GRAPHS + TB - 1) / TB, TB, 0, stream>>>(pooled, Wl, bl, out);
}

// Round 2
// 1002.469 us; speedup vs baseline: 1.5541x; 1.5541x over previous
//
#include <hip/hip_runtime.h>
#include <hip/hip_bf16.h>
#include <hip/hip_fp16.h>
#include <math.h>

#define N_NODES 100000
#define N_EDGES 3200000
#define N_GRAPHS 512
#define BN_EPS 1e-5f

// ---------------- CSR build ----------------

__global__ void k_count(const int* __restrict__ dst, int* __restrict__ cnt) {
    int e = blockIdx.x * blockDim.x + threadIdx.x;
    if (e < N_EDGES) atomicAdd(&cnt[dst[e]], 1);
}

__global__ void k_dis(const int* __restrict__ cnt, float* __restrict__ dis) {
    int n = blockIdx.x * blockDim.x + threadIdx.x;
    if (n < N_NODES) dis[n] = rsqrtf(1.0f + (float)cnt[n]);  // deg includes self-loop
}

// block-wise exclusive scan (1024/block)
__global__ void k_scan_block(const int* __restrict__ cnt, int* __restrict__ offs,
                             int* __restrict__ bsum) {
    __shared__ int sd[1024];
    int tid = threadIdx.x;
    int i = blockIdx.x * 1024 + tid;
    int v = (i < N_NODES) ? cnt[i] : 0;
    sd[tid] = v;
    __syncthreads();
    for (int off = 1; off < 1024; off <<= 1) {
        int t = (tid >= off) ? sd[tid - off] : 0;
        __syncthreads();
        sd[tid] += t;
        __syncthreads();
    }
    if (i < N_NODES) offs[i] = sd[tid] - v;  // exclusive
    if (tid == 1023) bsum[blockIdx.x] = sd[1023];
}

__global__ void k_scan_bsum(int* __restrict__ bsum, int nb, int* __restrict__ offs) {
    if (blockIdx.x == 0 && threadIdx.x == 0) {
        int run = 0;
        for (int b = 0; b < nb; ++b) { int t = bsum[b]; bsum[b] = run; run += t; }
        offs[N_NODES] = N_EDGES;
    }
}

__global__ void k_scan_add(int* __restrict__ offs, const int* __restrict__ bsum) {
    int i = blockIdx.x * blockDim.x + threadIdx.x;
    if (i < N_NODES) offs[i] += bsum[i >> 10];
}

__global__ void k_fill(const int* __restrict__ src, const int* __restrict__ dst,
                       const int* __restrict__ offs, int* __restrict__ cursor,
                       int* __restrict__ csr) {
    int e = blockIdx.x * blockDim.x + threadIdx.x;
    if (e < N_EDGES) {
        int d = dst[e];
        int pos = offs[d] + atomicAdd(&cursor[d], 1);
        csr[pos] = src[e];
    }
}

// ---------------- dense matmul + dis-prescale, fp16 output ----------------
// hWd[n,f] = dis[n] * sum_i h[n,i]*W[i,f], stored as half

template <int FIN, int FOUT>
__global__ void k_mm_h(const float* __restrict__ h, const float* __restrict__ W,
                       const float* __restrict__ dis, __half* __restrict__ out) {
    __shared__ float sW[FIN * FOUT];
    for (int i = threadIdx.x; i < FIN * FOUT; i += blockDim.x) sW[i] = W[i];
    __syncthreads();
    int gid = blockIdx.x * blockDim.x + threadIdx.x;
    if (gid >= N_NODES * FOUT) return;
    int n = gid / FOUT, f = gid % FOUT;
    float acc = 0.f;
#pragma unroll
    for (int i = 0; i < FIN; ++i) acc += h[n * FIN + i] * sW[i * FOUT + f];
    out[gid] = __float2half(acc * dis[n]);
}

// ---------------- GCN aggregation (wave-per-node, half4 gather) ----------------
// out[n] = dis[n] * ( sum_{s in nbr(n)} hWd[s] + hWd[n] )

struct alignas(8) h4 { __half2 a, b; };

template <int FOUT>
__global__ void k_agg_v2(const __half* __restrict__ hWd, const int* __restrict__ offs,
                         const int* __restrict__ csr, const float* __restrict__ dis,
                         float* __restrict__ out) {
    constexpr int LPE = FOUT / 4;     // lanes per edge-row (chunks of 4 features)
    constexpr int EPI = 64 / LPE;     // edges per wave-iteration
    int wave = threadIdx.x >> 6;
    int lane = threadIdx.x & 63;
    int node = blockIdx.x * (blockDim.x >> 6) + wave;
    if (node >= N_NODES) return;
    int chunk = lane % LPE;          // which 4-feature chunk
    int eg    = lane / LPE;          // which edge within an iteration

    int e0 = offs[node], e1 = offs[node + 1];
    float ax = 0.f, ay = 0.f, az = 0.f, aw = 0.f;

    const __half* hp = hWd + (size_t)chunk * 4;
    int e = e0 + eg;
    // 4-way unrolled main loop: 4 independent gathers in flight
    for (; e + 3 * EPI < e1; e += 4 * EPI) {
        int s0 = csr[e];
        int s1 = csr[e + EPI];
        int s2 = csr[e + 2 * EPI];
        int s3 = csr[e + 3 * EPI];
        h4 v0 = *(const h4*)(hp + (size_t)s0 * FOUT);
        h4 v1 = *(const h4*)(hp + (size_t)s1 * FOUT);
        h4 v2 = *(const h4*)(hp + (size_t)s2 * FOUT);
        h4 v3 = *(const h4*)(hp + (size_t)s3 * FOUT);
        ax += __low2float(v0.a) + __low2float(v1.a) + __low2float(v2.a) + __low2float(v3.a);
        ay += __high2float(v0.a) + __high2float(v1.a) + __high2float(v2.a) + __high2float(v3.a);
        az += __low2float(v0.b) + __low2float(v1.b) + __low2float(v2.b) + __low2float(v3.b);
        aw += __high2float(v0.b) + __high2float(v1.b) + __high2float(v2.b) + __high2float(v3.b);
    }
    for (; e < e1; e += EPI) {
        int s = csr[e];
        h4 v = *(const h4*)(hp + (size_t)s * FOUT);
        ax += __low2float(v.a);
        ay += __high2float(v.a);
        az += __low2float(v.b);
        aw += __high2float(v.b);
    }
    // self-loop term (edge-group 0 only)
    if (eg == 0) {
        h4 v = *(const h4*)(hp + (size_t)node * FOUT);
        ax += __low2float(v.a);
        ay += __high2float(v.a);
        az += __low2float(v.b);
        aw += __high2float(v.b);
    }
    // reduce across edge-groups (xor over lane bits >= log2(LPE))
#pragma unroll
    for (int off = LPE; off < 64; off <<= 1) {
        ax += __shfl_xor(ax, off, 64);
        ay += __shfl_xor(ay, off, 64);
        az += __shfl_xor(az, off, 64);
        aw += __shfl_xor(aw, off, 64);
    }
    if (lane < LPE) {
        float dn = dis[node];
        float4 r = make_float4(dn * ax, dn * ay, dn * az, dn * aw);
        *(float4*)(out + (size_t)node * FOUT + chunk * 4) = r;
    }
}

// ---------------- BN stats over y = relu(conv + bias) ----------------

template <int FOUT>
__global__ void k_stats(const float* __restrict__ conv, const float* __restrict__ bias,
                        float* __restrict__ stats) {
    constexpr int GP = 256 / FOUT;
    int f = threadIdx.x % FOUT, g = threadIdx.x / FOUT;
    float bf = bias[f];
    float s = 0.f, s2 = 0.f;
    for (int n = blockIdx.x * GP + g; n < N_NODES; n += gridDim.x * GP) {
        float y = conv[n * FOUT + f] + bf;
        y = y > 0.f ? y : 0.f;
        s += y;
        s2 += y * y;
    }
    __shared__ float ls[256], ls2[256];
    ls[threadIdx.x] = s;
    ls2[threadIdx.x] = s2;
    __syncthreads();
    if (g == 0) {
        for (int gg = 1; gg < GP; ++gg) {
            s += ls[gg * FOUT + f];
            s2 += ls2[gg * FOUT + f];
        }
        atomicAdd(&stats[f], s);
        atomicAdd(&stats[FOUT + f], s2);
    }
}

template <int FOUT>
__global__ void k_bnprep(const float* __restrict__ stats, const float* __restrict__ gamma,
                         const float* __restrict__ beta, float* __restrict__ bnp) {
    int f = threadIdx.x;
    if (f >= FOUT) return;
    float inv_n = 1.0f / (float)N_NODES;
    float m = stats[f] * inv_n;
    float v = stats[FOUT + f] * inv_n - m * m;
    float a = gamma[f] * rsqrtf(v + BN_EPS);
    bnp[f] = a;
    bnp[FOUT + f] = beta[f] - m * a;
}

template <int FOUT>
__global__ void k_apply(float* __restrict__ hc, const float* __restrict__ bias,
                        const float* __restrict__ bnp) {
    int gid = blockIdx.x * blockDim.x + threadIdx.x;
    if (gid >= N_NODES * FOUT) return;
    int f = gid % FOUT;
    float y = hc[gid] + bias[f];
    y = y > 0.f ? y : 0.f;
    hc[gid] = bnp[f] * y + bnp[FOUT + f];
}

// ---------------- pooling (batch_index sorted) + head ----------------

__device__ __forceinline__ int lower_bound_dev(const int* __restrict__ a, int val) {
    int lo = 0, hi = N_NODES;
    while (lo < hi) {
        int mid = (lo + hi) >> 1;
        if (a[mid] < val) lo = mid + 1; else hi = mid;
    }
    return lo;
}

__global__ void k_pool(const float* __restrict__ h, const int* __restrict__ batch,
                       float* __restrict__ pooled) {
    int g = blockIdx.x;       // 0..511
    int f = threadIdx.x;      // 0..127
    int s = lower_bound_dev(batch, g);
    int e = lower_bound_dev(batch, g + 1);
    float m = -INFINITY;
    for (int n = s; n < e; ++n) m = fmaxf(m, h[n * 128 + f]);
    pooled[g * 128 + f] = m;
}

__global__ void k_head(const float* __restrict__ pooled, const float* __restrict__ Wl,
                       const float* __restrict__ bl, float* __restrict__ out) {
    int g = blockIdx.x * blockDim.x + threadIdx.x;
    if (g >= N_GRAPHS) return;
    float l0 = bl[0], l1 = bl[1], l2 = bl[2];
    for (int i = 0; i < 128; ++i) {
        float p = pooled[g * 128 + i];
        l0 += p * Wl[i * 3 + 0];
        l1 += p * Wl[i * 3 + 1];
        l2 += p * Wl[i * 3 + 2];
    }
    float mx = fmaxf(l0, fmaxf(l1, l2));
    float lse = mx + logf(expf(l0 - mx) + expf(l1 - mx) + expf(l2 - mx));
    out[g * 3 + 0] = l0 - lse;
    out[g * 3 + 1] = l1 - lse;
    out[g * 3 + 2] = l2 - lse;
}

// ---------------- launch ----------------

extern "C" void kernel_launch(void* const* d_in, const int* in_sizes, int n_in,
                              void* d_out, int out_size, void* d_ws, size_t ws_size,
                              hipStream_t stream) {
    const float* x   = (const float*)d_in[0];
    const int* ei    = (const int*)d_in[1];
    const int* src   = ei;
    const int* dst   = ei + N_EDGES;
    const int* batch = (const int*)d_in[2];
    const float *W1 = (const float*)d_in[3],  *b1 = (const float*)d_in[4];
    const float *g1 = (const float*)d_in[5],  *be1 = (const float*)d_in[6];
    const float *W2 = (const float*)d_in[7],  *b2 = (const float*)d_in[8];
    const float *g2 = (const float*)d_in[9],  *be2 = (const float*)d_in[10];
    const float *W3 = (const float*)d_in[11], *b3 = (const float*)d_in[12];
    const float *g3 = (const float*)d_in[13], *be3 = (const float*)d_in[14];
    const float *Wl = (const float*)d_in[15], *bl = (const float*)d_in[16];
    float* out = (float*)d_out;

    // workspace carve (4-byte units)
    int* base = (int*)d_ws;
    size_t o = 0;
    int* cnt     = base + o; o += N_NODES;
    int* cursor  = base + o; o += N_NODES;
    float* stats = (float*)(base + o); o += 256;
    float* bnp   = (float*)(base + o); o += 256;
    int* offs    = base + o; o += N_NODES + 1;
    int* bsum    = base + o; o += 128;
    int* csr     = base + o; o += N_EDGES;
    float* dis   = (float*)(base + o); o += N_NODES;
    float* pooled= (float*)(base + o); o += (size_t)N_GRAPHS * 128;
    __half* bufH = (__half*)(base + o); o += (size_t)N_NODES * 64;  // N*128 halfs
    float* bufC  = (float*)(base + o); o += (size_t)N_NODES * 128;
    if (ws_size < o * 4) return;

    const int TB = 256;
    const int gridE = (N_EDGES + TB - 1) / TB;
    const int gridN = (N_NODES + TB - 1) / TB;
    const int nb_scan = (N_NODES + 1023) / 1024;  // 98
    const int gridAgg = (N_NODES + 3) / 4;        // 4 waves/block, wave-per-node

    // zero cnt + cursor
    hipMemsetAsync(base, 0, (size_t)2 * N_NODES * 4, stream);

    // CSR + norm
    k_count<<<gridE, TB, 0, stream>>>(dst, cnt);
    k_dis<<<gridN, TB, 0, stream>>>(cnt, dis);
    k_scan_block<<<nb_scan, 1024, 0, stream>>>(cnt, offs, bsum);
    k_scan_bsum<<<1, 1, 0, stream>>>(bsum, nb_scan, offs);
    k_scan_add<<<gridN, TB, 0, stream>>>(offs, bsum);
    k_fill<<<gridE, TB, 0, stream>>>(src, dst, offs, cursor, csr);

    // ---- layer 1: 2 -> 8 ----
    {
        const int g8 = (N_NODES * 8 + TB - 1) / TB;
        k_mm_h<2, 8><<<g8, TB, 0, stream>>>(x, W1, dis, bufH);
        k_agg_v2<8><<<gridAgg, TB, 0, stream>>>(bufH, offs, csr, dis, bufC);
        hipMemsetAsync(stats, 0, 1024, stream);
        k_stats<8><<<256, 256, 0, stream>>>(bufC, b1, stats);
        k_bnprep<8><<<1, 8, 0, stream>>>(stats, g1, be1, bnp);
        k_apply<8><<<g8, TB, 0, stream>>>(bufC, b1, bnp);
    }
    // ---- layer 2: 8 -> 32 ----
    {
        const int g32 = (N_NODES * 32 + TB - 1) / TB;
        k_mm_h<8, 32><<<g32, TB, 0, stream>>>(bufC, W2, dis, bufH);
        k_agg_v2<32><<<gridAgg, TB, 0, stream>>>(bufH, offs, csr, dis, bufC);
        hipMemsetAsync(stats, 0, 1024, stream);
        k_stats<32><<<256, 256, 0, stream>>>(bufC, b2, stats);
        k_bnprep<32><<<1, 32, 0, stream>>>(stats, g2, be2, bnp);
        k_apply<32><<<g32, TB, 0, stream>>>(bufC, b2, bnp);
    }
    // ---- layer 3: 32 -> 128 ----
    {
        const int g128 = (N_NODES * 128 + TB - 1) / TB;
        k_mm_h<32, 128><<<g128, TB, 0, stream>>>(bufC, W3, dis, bufH);
        k_agg_v2<128><<<gridAgg, TB, 0, stream>>>(bufH, offs, csr, dis, bufC);
        hipMemsetAsync(stats, 0, 1024, stream);
        k_stats<128><<<256, 256, 0, stream>>>(bufC, b3, stats);
        k_bnprep<128><<<1, 128, 0, stream>>>(stats, g3, be3, bnp);
        k_apply<128><<<g128, TB, 0, stream>>>(bufC, b3, bnp);
    }

    // pool + head
    k_pool<<<N_GRAPHS, 128, 0, stream>>>(bufC, batch, pooled);
    k_head<<<(N_GRAPHS + TB - 1) / TB, TB, 0, stream>>>(pooled, Wl, bl, out);
}